// Round 1
// baseline (754.197 us; speedup 1.0000x reference)
//
#include <hip/hip_runtime.h>
#include <hip/hip_bf16.h>
#include <math.h>

#define N_NODES 50000
#define D 128
#define LN_EPS 1e-5f

// ---------------- CSR build ----------------

__global__ void init_kernel(int* deg, int* total, int n) {
    int i = blockIdx.x * blockDim.x + threadIdx.x;
    if (i < n) deg[i] = 1;            // self-loop contributes 1 to degree
    if (i == 0) *total = 0;
}

__global__ void count_kernel(const int* __restrict__ dstA, int* deg, int E) {
    int e = blockIdx.x * blockDim.x + threadIdx.x;
    if (e < E) atomicAdd(&deg[dstA[e]], 1);
}

__global__ void node_setup(const int* __restrict__ deg, float* __restrict__ dinv,
                           int* __restrict__ startArr, int* __restrict__ cursor,
                           int* total, int* __restrict__ csr_src,
                           float* __restrict__ csr_w, int n) {
    int i = blockIdx.x * blockDim.x + threadIdx.x;
    if (i >= n) return;
    int d = deg[i];
    float di = rsqrtf((float)d);
    dinv[i] = di;
    int s = atomicAdd(total, d);      // bump-allocate this node's CSR range
    startArr[i] = s;
    csr_src[s] = i;                   // self-loop entry
    csr_w[s] = di * di;
    cursor[i] = s + 1;
}

__global__ void fill_kernel(const int* __restrict__ srcA, const int* __restrict__ dstA,
                            const float* __restrict__ dinv, int* cursor,
                            int* __restrict__ csr_src, float* __restrict__ csr_w, int E) {
    int e = blockIdx.x * blockDim.x + threadIdx.x;
    if (e >= E) return;
    int s = srcA[e], t = dstA[e];
    int p = atomicAdd(&cursor[t], 1);
    csr_src[p] = s;
    csr_w[p] = dinv[s] * dinv[t];
}

// ---------------- dense H = X @ W (f32, VALU) ----------------

__global__ __launch_bounds__(256) void gemm_kernel(const float* __restrict__ X,
                                                   const float* __restrict__ W,
                                                   float* __restrict__ H, int n) {
    __shared__ float Ws[D * D];       // 64 KB, exactly the static LDS limit
    for (int idx = threadIdx.x; idx < D * D / 4; idx += 256)
        ((float4*)Ws)[idx] = ((const float4*)W)[idx];
    __syncthreads();

    int lane = threadIdx.x & 63;
    int wid  = threadIdx.x >> 6;      // 4 waves/block, one row per wave
    int gw   = blockIdx.x * 4 + wid;
    int nw   = gridDim.x * 4;
    int c0   = lane * 2;

    for (int row = gw; row < n; row += nw) {
        const float* xr = X + (size_t)row * D;
        float a0 = 0.f, a1 = 0.f;
#pragma unroll 8
        for (int k = 0; k < D; ++k) {
            float xv = xr[k];                               // wave-uniform, L1 broadcast
            float2 w = *(const float2*)&Ws[k * D + c0];     // ds_read_b64, 2-way (free)
            a0 = fmaf(xv, w.x, a0);
            a1 = fmaf(xv, w.y, a1);
        }
        float2 o; o.x = a0; o.y = a1;
        *(float2*)&H[(size_t)row * D + c0] = o;
    }
}

// ------- gather-aggregate + bias + LayerNorm + ELU (fused epilogue) -------

__global__ __launch_bounds__(256) void agg_ln_elu(
        const float* __restrict__ H, const int* __restrict__ csr_src,
        const float* __restrict__ csr_w, const int* __restrict__ startArr,
        const int* __restrict__ deg,
        const float* __restrict__ bias, const float* __restrict__ gamma,
        const float* __restrict__ beta, float* __restrict__ out, int n) {
    int lane = threadIdx.x & 63;
    int wid  = threadIdx.x >> 6;
    int node = blockIdx.x * 4 + wid;  // one wave per node
    if (node >= n) return;

    int s   = startArr[node];
    int cnt = deg[node];
    int c0  = lane * 2;

    float a0 = 0.f, a1 = 0.f;
    int j = 0;
    for (; j + 2 <= cnt; j += 2) {    // 2-way unroll for MLP
        int   s0 = csr_src[s + j],  s1 = csr_src[s + j + 1];
        float w0 = csr_w[s + j],    w1 = csr_w[s + j + 1];
        float2 g0 = *(const float2*)&H[(size_t)s0 * D + c0];
        float2 g1 = *(const float2*)&H[(size_t)s1 * D + c0];
        a0 = fmaf(w0, g0.x, a0); a1 = fmaf(w0, g0.y, a1);
        a0 = fmaf(w1, g1.x, a0); a1 = fmaf(w1, g1.y, a1);
    }
    if (j < cnt) {
        int   s0 = csr_src[s + j];
        float w0 = csr_w[s + j];
        float2 g0 = *(const float2*)&H[(size_t)s0 * D + c0];
        a0 = fmaf(w0, g0.x, a0); a1 = fmaf(w0, g0.y, a1);
    }

    a0 += bias[c0]; a1 += bias[c0 + 1];

    // LayerNorm over the 128 features held across the wave (2/lane)
    float sum = a0 + a1;
    float sq  = a0 * a0 + a1 * a1;
#pragma unroll
    for (int m = 32; m > 0; m >>= 1) {
        sum += __shfl_xor(sum, m, 64);
        sq  += __shfl_xor(sq,  m, 64);
    }
    float mean = sum * (1.f / 128.f);
    float var  = sq * (1.f / 128.f) - mean * mean;
    float rstd = rsqrtf(var + LN_EPS);

    float y0 = (a0 - mean) * rstd * gamma[c0]     + beta[c0];
    float y1 = (a1 - mean) * rstd * gamma[c0 + 1] + beta[c0 + 1];
    y0 = y0 > 0.f ? y0 : expm1f(y0);   // ELU (alpha=1)
    y1 = y1 > 0.f ? y1 : expm1f(y1);

    float2 o; o.x = y0; o.y = y1;
    *(float2*)&out[(size_t)node * D + c0] = o;
}

// ---------------- launcher ----------------

extern "C" void kernel_launch(void* const* d_in, const int* in_sizes, int n_in,
                              void* d_out, int out_size, void* d_ws, size_t ws_size,
                              hipStream_t stream) {
    const float* x   = (const float*)d_in[0];
    const int*  eidx = (const int*)d_in[1];
    const float* W1  = (const float*)d_in[2];
    const float* b1  = (const float*)d_in[3];
    const float* g1  = (const float*)d_in[4];
    const float* be1 = (const float*)d_in[5];
    const float* W2  = (const float*)d_in[6];
    const float* b2  = (const float*)d_in[7];
    const float* g2  = (const float*)d_in[8];
    const float* be2 = (const float*)d_in[9];

    int E = in_sizes[1] / 2;
    const int* srcA = eidx;
    const int* dstA = eidx + E;

    char* p = (char*)d_ws;
    auto alloc = [&](size_t bytes) {
        char* r = p;
        p += (bytes + 255) & ~(size_t)255;
        return r;
    };
    int*   deg      = (int*)alloc((size_t)N_NODES * 4);
    float* dinv     = (float*)alloc((size_t)N_NODES * 4);
    int*   startArr = (int*)alloc((size_t)N_NODES * 4);
    int*   cursor   = (int*)alloc((size_t)N_NODES * 4);
    int*   total    = (int*)alloc(4);
    int*   csr_src  = (int*)alloc((size_t)(E + N_NODES) * 4);
    float* csr_w    = (float*)alloc((size_t)(E + N_NODES) * 4);
    float* h        = (float*)alloc((size_t)N_NODES * D * 4);
    float* x2       = (float*)alloc((size_t)N_NODES * D * 4);
    float* outp     = (float*)d_out;

    int nb = (N_NODES + 255) / 256;
    int eb = (E + 255) / 256;
    int ab = (N_NODES + 3) / 4;       // 4 waves (nodes) per block

    init_kernel <<<nb, 256, 0, stream>>>(deg, total, N_NODES);
    count_kernel<<<eb, 256, 0, stream>>>(dstA, deg, E);
    node_setup  <<<nb, 256, 0, stream>>>(deg, dinv, startArr, cursor, total,
                                         csr_src, csr_w, N_NODES);
    fill_kernel <<<eb, 256, 0, stream>>>(srcA, dstA, dinv, cursor,
                                         csr_src, csr_w, E);

    gemm_kernel <<<1024, 256, 0, stream>>>(x, W1, h, N_NODES);
    agg_ln_elu  <<<ab, 256, 0, stream>>>(h, csr_src, csr_w, startArr, deg,
                                         b1, g1, be1, x2, N_NODES);
    gemm_kernel <<<1024, 256, 0, stream>>>(x2, W2, h, N_NODES);
    agg_ln_elu  <<<ab, 256, 0, stream>>>(h, csr_src, csr_w, startArr, deg,
                                         b2, g2, be2, outp, N_NODES);
}

// Round 2
// 421.311 us; speedup vs baseline: 1.7901x; 1.7901x over previous
//
#include <hip/hip_runtime.h>
#include <hip/hip_bf16.h>
#include <math.h>

#define N_NODES 50000
#define D 128
#define LN_EPS 1e-5f

typedef unsigned short u16;
typedef __attribute__((ext_vector_type(8))) short bf16x8;
typedef __attribute__((ext_vector_type(4))) float f32x4;

static __device__ __forceinline__ u16 f2bf(float f) {   // RNE f32->bf16
    union { float f; unsigned u; } v; v.f = f;
    unsigned r = v.u + 0x7fff + ((v.u >> 16) & 1);
    return (u16)(r >> 16);
}
static __device__ __forceinline__ float bf2f(u16 b) {
    union { unsigned u; float f; } v; v.u = ((unsigned)b) << 16;
    return v.f;
}

// ---------------- CSR build ----------------

__global__ void init_kernel(int* deg, int* total, int n) {
    int i = blockIdx.x * blockDim.x + threadIdx.x;
    if (i < n) deg[i] = 1;            // self-loop
    if (i == 0) *total = 0;
}

__global__ void count_kernel(const int* __restrict__ dstA, int* deg, int E) {
    int e = blockIdx.x * blockDim.x + threadIdx.x;
    if (e < E) atomicAdd(&deg[dstA[e]], 1);
}

__global__ void node_setup(const int* __restrict__ deg, float* __restrict__ dinv,
                           int* __restrict__ startArr, int* __restrict__ cursor,
                           int* total, int2* __restrict__ csr, int n) {
    int i = blockIdx.x * blockDim.x + threadIdx.x;
    if (i >= n) return;
    int d = deg[i];
    float di = rsqrtf((float)d);
    dinv[i] = di;
    int s = atomicAdd(total, d);      // bump-allocate this node's CSR range
    startArr[i] = s;
    int2 v; v.x = i; v.y = __float_as_int(di * di);
    csr[s] = v;                       // self-loop entry
    cursor[i] = s + 1;
}

__global__ void fill_kernel(const int* __restrict__ srcA, const int* __restrict__ dstA,
                            const float* __restrict__ dinv, int* cursor,
                            int2* __restrict__ csr, int E) {
    int e = blockIdx.x * blockDim.x + threadIdx.x;
    if (e >= E) return;
    int s = srcA[e], t = dstA[e];
    int p = atomicAdd(&cursor[t], 1);
    int2 v; v.x = s; v.y = __float_as_int(dinv[s] * dinv[t]);
    csr[p] = v;                       // single 8B scattered store per edge
}

// ---------------- f32 -> bf16 convert ----------------

__global__ void cvt_bf16(const float* __restrict__ in, u16* __restrict__ out, int n4) {
    int i = blockIdx.x * blockDim.x + threadIdx.x;
    if (i >= n4) return;
    float4 f = ((const float4*)in)[i];
    ushort4 o;
    o.x = f2bf(f.x); o.y = f2bf(f.y); o.z = f2bf(f.z); o.w = f2bf(f.w);
    ((ushort4*)out)[i] = o;
}

// ---------------- H = X @ W via bf16 MFMA ----------------
// A: X bf16 [n x 128] row-major. W: f32 [128k x 128n] row-major, transposed
// into padded LDS as bf16. C: H bf16 [n x 128].

__global__ __launch_bounds__(256) void gemm_mfma(const u16* __restrict__ Xb,
                                                 const float* __restrict__ W,
                                                 u16* __restrict__ H, int n) {
    __shared__ __align__(16) u16 WT[D][136];   // W^T, +8 pad breaks bank stride
    for (int idx = threadIdx.x; idx < D * D; idx += 256) {
        int k = idx >> 7, c = idx & 127;       // coalesced read of W[k][c]
        WT[c][k] = f2bf(W[idx]);
    }
    __syncthreads();

    int lane = threadIdx.x & 63;
    int wid  = threadIdx.x >> 6;
    int r    = lane & 15;                      // A-row / B-col within tile
    int kg   = lane >> 4;                      // k-group (8 elems each)

    int rb0 = blockIdx.x * 4 + wid;            // 16-row block per wave
    int nrb = gridDim.x * 4;
    for (int rb = rb0; rb < n / 16; rb += nrb) {
        int row0 = rb * 16;
        const u16* xp = Xb + (size_t)(row0 + r) * D + kg * 8;
        bf16x8 a0 = *(const bf16x8*)(xp);
        bf16x8 a1 = *(const bf16x8*)(xp + 32);
        bf16x8 a2 = *(const bf16x8*)(xp + 64);
        bf16x8 a3 = *(const bf16x8*)(xp + 96);
#pragma unroll
        for (int t = 0; t < 8; ++t) {          // 8 col-tiles of 16
            const u16* wp = &WT[t * 16 + r][kg * 8];
            f32x4 acc = {0.f, 0.f, 0.f, 0.f};
            acc = __builtin_amdgcn_mfma_f32_16x16x32_bf16(a0, *(const bf16x8*)(wp),      acc, 0, 0, 0);
            acc = __builtin_amdgcn_mfma_f32_16x16x32_bf16(a1, *(const bf16x8*)(wp + 32), acc, 0, 0, 0);
            acc = __builtin_amdgcn_mfma_f32_16x16x32_bf16(a2, *(const bf16x8*)(wp + 64), acc, 0, 0, 0);
            acc = __builtin_amdgcn_mfma_f32_16x16x32_bf16(a3, *(const bf16x8*)(wp + 96), acc, 0, 0, 0);
            // C/D: col = lane&15, row = (lane>>4)*4 + i   [m89-verified layout]
#pragma unroll
            for (int i = 0; i < 4; ++i)
                H[(size_t)(row0 + kg * 4 + i) * D + t * 16 + r] = f2bf(acc[i]);
        }
    }
}

// ------- gather-aggregate(bf16) + bias + LayerNorm + ELU, fused -------

template <int WRITE_BF16>
__global__ __launch_bounds__(256) void agg_ln_elu(
        const u16* __restrict__ H, const int2* __restrict__ csr,
        const int* __restrict__ startArr, const int* __restrict__ deg,
        const float* __restrict__ bias, const float* __restrict__ gamma,
        const float* __restrict__ beta, void* __restrict__ outv, int n) {
    int lane = threadIdx.x & 63;
    int wid  = threadIdx.x >> 6;
    int node = blockIdx.x * 4 + wid;           // one wave per node
    if (node >= n) return;

    int s   = startArr[node];
    int cnt = deg[node];
    int c0  = lane * 2;

    float a0 = 0.f, a1 = 0.f;
    int j = 0;
    for (; j + 4 <= cnt; j += 4) {             // 4-way MLP unroll
        int2 e0 = csr[s + j], e1 = csr[s + j + 1], e2 = csr[s + j + 2], e3 = csr[s + j + 3];
        ushort2 g0 = *(const ushort2*)&H[(size_t)e0.x * D + c0];
        ushort2 g1 = *(const ushort2*)&H[(size_t)e1.x * D + c0];
        ushort2 g2 = *(const ushort2*)&H[(size_t)e2.x * D + c0];
        ushort2 g3 = *(const ushort2*)&H[(size_t)e3.x * D + c0];
        float w0 = __int_as_float(e0.y), w1 = __int_as_float(e1.y);
        float w2 = __int_as_float(e2.y), w3 = __int_as_float(e3.y);
        a0 = fmaf(w0, bf2f(g0.x), a0); a1 = fmaf(w0, bf2f(g0.y), a1);
        a0 = fmaf(w1, bf2f(g1.x), a0); a1 = fmaf(w1, bf2f(g1.y), a1);
        a0 = fmaf(w2, bf2f(g2.x), a0); a1 = fmaf(w2, bf2f(g2.y), a1);
        a0 = fmaf(w3, bf2f(g3.x), a0); a1 = fmaf(w3, bf2f(g3.y), a1);
    }
    for (; j < cnt; ++j) {
        int2 e0 = csr[s + j];
        ushort2 g0 = *(const ushort2*)&H[(size_t)e0.x * D + c0];
        float w0 = __int_as_float(e0.y);
        a0 = fmaf(w0, bf2f(g0.x), a0); a1 = fmaf(w0, bf2f(g0.y), a1);
    }

    a0 += bias[c0]; a1 += bias[c0 + 1];

    float sum = a0 + a1;
    float sq  = a0 * a0 + a1 * a1;
#pragma unroll
    for (int m = 32; m > 0; m >>= 1) {
        sum += __shfl_xor(sum, m, 64);
        sq  += __shfl_xor(sq,  m, 64);
    }
    float mean = sum * (1.f / 128.f);
    float var  = sq * (1.f / 128.f) - mean * mean;
    float rstd = rsqrtf(var + LN_EPS);

    float y0 = (a0 - mean) * rstd * gamma[c0]     + beta[c0];
    float y1 = (a1 - mean) * rstd * gamma[c0 + 1] + beta[c0 + 1];
    y0 = y0 > 0.f ? y0 : expm1f(y0);            // ELU
    y1 = y1 > 0.f ? y1 : expm1f(y1);

    if (WRITE_BF16) {
        ushort2 o; o.x = f2bf(y0); o.y = f2bf(y1);
        *(ushort2*)((u16*)outv + (size_t)node * D + c0) = o;
    } else {
        float2 o; o.x = y0; o.y = y1;
        *(float2*)((float*)outv + (size_t)node * D + c0) = o;
    }
}

// ---------------- launcher ----------------

extern "C" void kernel_launch(void* const* d_in, const int* in_sizes, int n_in,
                              void* d_out, int out_size, void* d_ws, size_t ws_size,
                              hipStream_t stream) {
    const float* x   = (const float*)d_in[0];
    const int*  eidx = (const int*)d_in[1];
    const float* W1  = (const float*)d_in[2];
    const float* b1  = (const float*)d_in[3];
    const float* g1  = (const float*)d_in[4];
    const float* be1 = (const float*)d_in[5];
    const float* W2  = (const float*)d_in[6];
    const float* b2  = (const float*)d_in[7];
    const float* g2  = (const float*)d_in[8];
    const float* be2 = (const float*)d_in[9];

    int E = in_sizes[1] / 2;
    const int* srcA = eidx;
    const int* dstA = eidx + E;

    char* p = (char*)d_ws;
    auto alloc = [&](size_t bytes) {
        char* r = p;
        p += (bytes + 255) & ~(size_t)255;
        return r;
    };
    int*   deg      = (int*)alloc((size_t)N_NODES * 4);
    float* dinv     = (float*)alloc((size_t)N_NODES * 4);
    int*   startArr = (int*)alloc((size_t)N_NODES * 4);
    int*   cursor   = (int*)alloc((size_t)N_NODES * 4);
    int*   total    = (int*)alloc(4);
    int2*  csr      = (int2*)alloc((size_t)(E + N_NODES) * 8);
    u16*   xb       = (u16*)alloc((size_t)N_NODES * D * 2);
    u16*   h        = (u16*)alloc((size_t)N_NODES * D * 2);
    u16*   x2b      = (u16*)alloc((size_t)N_NODES * D * 2);
    float* outp     = (float*)d_out;

    int nb = (N_NODES + 255) / 256;
    int eb = (E + 255) / 256;
    int ab = (N_NODES + 3) / 4;
    int cb = (N_NODES * D / 4 + 255) / 256;
    int gb = (N_NODES / 16 + 3) / 4;           // 782 blocks, 1 row-block/wave

    init_kernel <<<nb, 256, 0, stream>>>(deg, total, N_NODES);
    count_kernel<<<eb, 256, 0, stream>>>(dstA, deg, E);
    node_setup  <<<nb, 256, 0, stream>>>(deg, dinv, startArr, cursor, total, csr, N_NODES);
    fill_kernel <<<eb, 256, 0, stream>>>(srcA, dstA, dinv, cursor, csr, E);

    cvt_bf16    <<<cb, 256, 0, stream>>>(x, xb, N_NODES * D / 4);
    gemm_mfma   <<<gb, 256, 0, stream>>>(xb, W1, h, N_NODES);
    agg_ln_elu<1><<<ab, 256, 0, stream>>>(h, csr, startArr, deg, b1, g1, be1, x2b, N_NODES);
    gemm_mfma   <<<gb, 256, 0, stream>>>(x2b, W2, h, N_NODES);
    agg_ln_elu<0><<<ab, 256, 0, stream>>>(h, csr, startArr, deg, b2, g2, be2, outp, N_NODES);
}

// Round 3
// 295.327 us; speedup vs baseline: 2.5538x; 1.4266x over previous
//
#include <hip/hip_runtime.h>
#include <hip/hip_bf16.h>
#include <math.h>

#define N_NODES 50000
#define D 128
#define LN_EPS 1e-5f
#define NB 391            // ceil(50000/128): buckets of 128 dst nodes
#define CHUNK 4096        // edges per partition workgroup

typedef unsigned int u32;
typedef unsigned short u16;
typedef __attribute__((ext_vector_type(8))) short bf16x8;
typedef __attribute__((ext_vector_type(4))) float f32x4;

static __device__ __forceinline__ u16 f2bf(float f) {   // RNE f32->bf16
    union { float f; unsigned u; } v; v.f = f;
    unsigned r = v.u + 0x7fff + ((v.u >> 16) & 1);
    return (u16)(r >> 16);
}
static __device__ __forceinline__ float bf2f(u16 b) {
    union { unsigned u; float f; } v; v.u = ((unsigned)b) << 16;
    return v.f;
}

// ---------- K1: per-bucket edge histogram (LDS-staged) ----------
__global__ __launch_bounds__(256) void bucket_hist(const int* __restrict__ dstA,
                                                   u32* __restrict__ bucketCount, int E) {
    __shared__ u32 hist[NB];
    for (int b = threadIdx.x; b < NB; b += 256) hist[b] = 0;
    __syncthreads();
    int stride = gridDim.x * 256;
    for (int e = blockIdx.x * 256 + threadIdx.x; e < E; e += stride)
        atomicAdd(&hist[((u32)dstA[e]) >> 7], 1u);
    __syncthreads();
    for (int b = threadIdx.x; b < NB; b += 256)
        if (hist[b]) atomicAdd(&bucketCount[b], hist[b]);
}

// ---------- K2: exclusive scan over NB buckets (1 block) ----------
__global__ void scan_kernel(const u32* __restrict__ bucketCount, u32* __restrict__ ebStart,
                            u32* __restrict__ ebCursor, u32* __restrict__ csrStart) {
    __shared__ u32 s[512];
    int t = threadIdx.x;
    u32 my = (t < NB) ? bucketCount[t] : 0u;
    s[t] = my;
    __syncthreads();
    for (int off = 1; off < 512; off <<= 1) {
        u32 v = s[t] + ((t >= off) ? s[t - off] : 0u);
        __syncthreads();
        s[t] = v;
        __syncthreads();
    }
    if (t < NB) {
        u32 excl = s[t] - my;                 // edges before this bucket
        ebStart[t]  = excl;
        ebCursor[t] = excl;
        csrStart[t] = excl + 128u * (u32)t;   // + self-loop slots of prior buckets
    }
}

// ---------- K3: partition edges into bucket-dense packed array ----------
__global__ __launch_bounds__(256) void partition_kernel(const int* __restrict__ srcA,
                                                        const int* __restrict__ dstA,
                                                        u32* __restrict__ ebCursor,
                                                        u32* __restrict__ ebuf, int E) {
    __shared__ u32 cntA[NB], cntB[NB], base[NB];
    int t = threadIdx.x;
    for (int b = t; b < NB; b += 256) { cntA[b] = 0; cntB[b] = 0; }
    __syncthreads();
    int e0 = blockIdx.x * CHUNK;
    int e1 = min(e0 + CHUNK, E);
    for (int e = e0 + t; e < e1; e += 256)
        atomicAdd(&cntA[((u32)dstA[e]) >> 7], 1u);
    __syncthreads();
    for (int b = t; b < NB; b += 256)
        if (cntA[b]) base[b] = atomicAdd(&ebCursor[b], cntA[b]);
    __syncthreads();
    for (int e = e0 + t; e < e1; e += 256) {
        u32 d = (u32)dstA[e], sv = (u32)srcA[e];
        u32 b = d >> 7;
        u32 off = atomicAdd(&cntB[b], 1u);
        ebuf[base[b] + off] = (sv << 16) | d;     // src,dst < 65536
    }
}

// ---------- K4: per-bucket degree/prefix/CSR build (1 wg per bucket) ----------
__global__ __launch_bounds__(256) void bucket_build(const u32* __restrict__ ebuf,
                                                    const u32* __restrict__ ebStart,
                                                    const u32* __restrict__ ebEnd,
                                                    const u32* __restrict__ csrStart,
                                                    u16* __restrict__ csr_src,
                                                    int* __restrict__ startArr,
                                                    int* __restrict__ deg,
                                                    float* __restrict__ dinv) {
    int b = blockIdx.x, t = threadIdx.x;
    int nodeBase = b << 7;
    int nNodes = min(128, N_NODES - nodeBase);
    __shared__ u32 cnt[128], sc[128], cur[128];
    if (t < 128) cnt[t] = 0;
    __syncthreads();
    u32 eb0 = ebStart[b], eb1 = ebEnd[b];
    for (u32 e = eb0 + t; e < eb1; e += 256)
        atomicAdd(&cnt[ebuf[e] & 127u], 1u);
    __syncthreads();
    if (t < 128) sc[t] = (t < nNodes) ? cnt[t] + 1u : 0u;   // +1 self-loop
    __syncthreads();
    for (int off = 1; off < 128; off <<= 1) {
        u32 v = 0;
        if (t < 128) v = sc[t] + ((t >= off) ? sc[t - off] : 0u);
        __syncthreads();
        if (t < 128) sc[t] = v;
        __syncthreads();
    }
    u32 cs = csrStart[b];
    if (t < nNodes) {
        u32 val = cnt[t] + 1u;
        u32 excl = sc[t] - val;
        int i = nodeBase + t;
        deg[i] = (int)val;
        dinv[i] = rsqrtf((float)val);
        u32 sa = cs + excl;
        startArr[i] = (int)sa;
        csr_src[sa] = (u16)i;                  // self-loop first
        cur[t] = excl + 1u;
    }
    __syncthreads();
    for (u32 e = eb0 + t; e < eb1; e += 256) {
        u32 p = ebuf[e];
        u32 pos = atomicAdd(&cur[p & 127u], 1u);
        csr_src[cs + pos] = (u16)(p >> 16);
    }
}

// ---------- H = X @ W via bf16 MFMA (A from f32 or bf16) ----------
static __device__ __forceinline__ bf16x8 packf8(const float* p) {
    float4 f0 = *(const float4*)p;
    float4 f1 = *(const float4*)(p + 4);
    bf16x8 r;
    r[0] = (short)f2bf(f0.x); r[1] = (short)f2bf(f0.y);
    r[2] = (short)f2bf(f0.z); r[3] = (short)f2bf(f0.w);
    r[4] = (short)f2bf(f1.x); r[5] = (short)f2bf(f1.y);
    r[6] = (short)f2bf(f1.z); r[7] = (short)f2bf(f1.w);
    return r;
}

template <int SRCF32>
__global__ __launch_bounds__(256) void gemm_mfma(const void* __restrict__ Xv,
                                                 const float* __restrict__ W,
                                                 u16* __restrict__ H, int n) {
    __shared__ __align__(16) u16 WT[D][136];   // W^T, +8 pad
    for (int idx = threadIdx.x; idx < D * D; idx += 256) {
        int k = idx >> 7, c = idx & 127;
        WT[c][k] = f2bf(W[idx]);
    }
    __syncthreads();

    int lane = threadIdx.x & 63;
    int wid  = threadIdx.x >> 6;
    int r    = lane & 15;
    int kg   = lane >> 4;

    int rb0 = blockIdx.x * 4 + wid;
    int nrb = gridDim.x * 4;
    for (int rb = rb0; rb < n / 16; rb += nrb) {
        int row0 = rb * 16;
        bf16x8 a0, a1, a2, a3;
        if (SRCF32) {
            const float* xp = (const float*)Xv + (size_t)(row0 + r) * D + kg * 8;
            a0 = packf8(xp); a1 = packf8(xp + 32); a2 = packf8(xp + 64); a3 = packf8(xp + 96);
        } else {
            const u16* xp = (const u16*)Xv + (size_t)(row0 + r) * D + kg * 8;
            a0 = *(const bf16x8*)(xp);      a1 = *(const bf16x8*)(xp + 32);
            a2 = *(const bf16x8*)(xp + 64); a3 = *(const bf16x8*)(xp + 96);
        }
#pragma unroll
        for (int tile = 0; tile < 8; ++tile) {
            const u16* wp = &WT[tile * 16 + r][kg * 8];
            f32x4 acc = {0.f, 0.f, 0.f, 0.f};
            acc = __builtin_amdgcn_mfma_f32_16x16x32_bf16(a0, *(const bf16x8*)(wp),      acc, 0, 0, 0);
            acc = __builtin_amdgcn_mfma_f32_16x16x32_bf16(a1, *(const bf16x8*)(wp + 32), acc, 0, 0, 0);
            acc = __builtin_amdgcn_mfma_f32_16x16x32_bf16(a2, *(const bf16x8*)(wp + 64), acc, 0, 0, 0);
            acc = __builtin_amdgcn_mfma_f32_16x16x32_bf16(a3, *(const bf16x8*)(wp + 96), acc, 0, 0, 0);
#pragma unroll
            for (int i = 0; i < 4; ++i)
                H[(size_t)(row0 + kg * 4 + i) * D + tile * 16 + r] = f2bf(acc[i]);
        }
    }
}

// ------- gather-aggregate + bias + LN + ELU; 2 nodes per wave -------
template <int WRITE_BF16>
__global__ __launch_bounds__(256) void agg_ln_elu(
        const u16* __restrict__ H, const u16* __restrict__ csr_src,
        const int* __restrict__ startArr, const int* __restrict__ deg,
        const float* __restrict__ dinv,
        const float* __restrict__ bias, const float* __restrict__ gamma,
        const float* __restrict__ beta, void* __restrict__ outv) {
    int lane = threadIdx.x & 63;
    int wid  = threadIdx.x >> 6;
    int half = lane >> 5;
    int l    = lane & 31;
    int node = blockIdx.x * 8 + wid * 2 + half;   // 50000 = 6250 blocks * 8 exact

    int s    = startArr[node];
    int cnt  = deg[node];
    float dn = dinv[node];
    int c0   = l * 4;

    float a0 = 0.f, a1 = 0.f, a2 = 0.f, a3 = 0.f;
    int j = 0;
    for (; j + 4 <= cnt; j += 4) {
        u32 s0 = csr_src[s + j],     s1 = csr_src[s + j + 1];
        u32 s2 = csr_src[s + j + 2], s3 = csr_src[s + j + 3];
        float w0 = dinv[s0] * dn, w1 = dinv[s1] * dn;
        float w2 = dinv[s2] * dn, w3 = dinv[s3] * dn;
        ushort4 g0 = *(const ushort4*)&H[(size_t)s0 * D + c0];
        ushort4 g1 = *(const ushort4*)&H[(size_t)s1 * D + c0];
        ushort4 g2 = *(const ushort4*)&H[(size_t)s2 * D + c0];
        ushort4 g3 = *(const ushort4*)&H[(size_t)s3 * D + c0];
        a0 = fmaf(w0, bf2f(g0.x), a0); a1 = fmaf(w0, bf2f(g0.y), a1);
        a2 = fmaf(w0, bf2f(g0.z), a2); a3 = fmaf(w0, bf2f(g0.w), a3);
        a0 = fmaf(w1, bf2f(g1.x), a0); a1 = fmaf(w1, bf2f(g1.y), a1);
        a2 = fmaf(w1, bf2f(g1.z), a2); a3 = fmaf(w1, bf2f(g1.w), a3);
        a0 = fmaf(w2, bf2f(g2.x), a0); a1 = fmaf(w2, bf2f(g2.y), a1);
        a2 = fmaf(w2, bf2f(g2.z), a2); a3 = fmaf(w2, bf2f(g2.w), a3);
        a0 = fmaf(w3, bf2f(g3.x), a0); a1 = fmaf(w3, bf2f(g3.y), a1);
        a2 = fmaf(w3, bf2f(g3.z), a2); a3 = fmaf(w3, bf2f(g3.w), a3);
    }
    for (; j < cnt; ++j) {
        u32 s0 = csr_src[s + j];
        float w0 = dinv[s0] * dn;
        ushort4 g0 = *(const ushort4*)&H[(size_t)s0 * D + c0];
        a0 = fmaf(w0, bf2f(g0.x), a0); a1 = fmaf(w0, bf2f(g0.y), a1);
        a2 = fmaf(w0, bf2f(g0.z), a2); a3 = fmaf(w0, bf2f(g0.w), a3);
    }

    float4 bv = *(const float4*)&bias[c0];
    a0 += bv.x; a1 += bv.y; a2 += bv.z; a3 += bv.w;

    float sum = a0 + a1 + a2 + a3;
    float sq  = a0 * a0 + a1 * a1 + a2 * a2 + a3 * a3;
#pragma unroll
    for (int m = 16; m > 0; m >>= 1) {       // reduce within 32-lane half
        sum += __shfl_xor(sum, m, 64);
        sq  += __shfl_xor(sq,  m, 64);
    }
    float mean = sum * (1.f / 128.f);
    float var  = sq * (1.f / 128.f) - mean * mean;
    float rstd = rsqrtf(var + LN_EPS);

    float4 gv = *(const float4*)&gamma[c0];
    float4 ev = *(const float4*)&beta[c0];
    float y0 = (a0 - mean) * rstd * gv.x + ev.x;
    float y1 = (a1 - mean) * rstd * gv.y + ev.y;
    float y2 = (a2 - mean) * rstd * gv.z + ev.z;
    float y3 = (a3 - mean) * rstd * gv.w + ev.w;
    y0 = y0 > 0.f ? y0 : expm1f(y0);
    y1 = y1 > 0.f ? y1 : expm1f(y1);
    y2 = y2 > 0.f ? y2 : expm1f(y2);
    y3 = y3 > 0.f ? y3 : expm1f(y3);

    if (WRITE_BF16) {
        ushort4 o;
        o.x = f2bf(y0); o.y = f2bf(y1); o.z = f2bf(y2); o.w = f2bf(y3);
        *(ushort4*)((u16*)outv + (size_t)node * D + c0) = o;
    } else {
        float4 o; o.x = y0; o.y = y1; o.z = y2; o.w = y3;
        *(float4*)((float*)outv + (size_t)node * D + c0) = o;
    }
}

// ---------------- launcher ----------------
extern "C" void kernel_launch(void* const* d_in, const int* in_sizes, int n_in,
                              void* d_out, int out_size, void* d_ws, size_t ws_size,
                              hipStream_t stream) {
    const float* x   = (const float*)d_in[0];
    const int*  eidx = (const int*)d_in[1];
    const float* W1  = (const float*)d_in[2];
    const float* b1  = (const float*)d_in[3];
    const float* g1  = (const float*)d_in[4];
    const float* be1 = (const float*)d_in[5];
    const float* W2  = (const float*)d_in[6];
    const float* b2  = (const float*)d_in[7];
    const float* g2  = (const float*)d_in[8];
    const float* be2 = (const float*)d_in[9];

    int E = in_sizes[1] / 2;
    const int* srcA = eidx;
    const int* dstA = eidx + E;

    char* p = (char*)d_ws;
    auto alloc = [&](size_t bytes) {
        char* r = p;
        p += (bytes + 255) & ~(size_t)255;
        return r;
    };
    u32*   bucketCount = (u32*)alloc((size_t)NB * 4);
    u32*   ebStart     = (u32*)alloc((size_t)NB * 4);
    u32*   ebCursor    = (u32*)alloc((size_t)NB * 4);
    u32*   csrStart    = (u32*)alloc((size_t)NB * 4);
    u32*   ebuf        = (u32*)alloc((size_t)E * 4);
    u16*   csr_src     = (u16*)alloc((size_t)(E + N_NODES) * 2);
    int*   startArr    = (int*)alloc((size_t)N_NODES * 4);
    int*   deg         = (int*)alloc((size_t)N_NODES * 4);
    float* dinv        = (float*)alloc((size_t)N_NODES * 4);
    u16*   h           = (u16*)alloc((size_t)N_NODES * D * 2);
    u16*   x2b         = (u16*)alloc((size_t)N_NODES * D * 2);
    float* outp        = (float*)d_out;

    int pb = (E + CHUNK - 1) / CHUNK;          // 391 partition blocks
    int gb = (N_NODES / 16 + 3) / 4;           // 782 gemm blocks
    int ab = N_NODES / 8;                      // 6250 agg blocks (exact)

    hipMemsetAsync(bucketCount, 0, (size_t)NB * 4, stream);
    bucket_hist     <<<512, 256, 0, stream>>>(dstA, bucketCount, E);
    scan_kernel     <<<1, 512, 0, stream>>>(bucketCount, ebStart, ebCursor, csrStart);
    partition_kernel<<<pb, 256, 0, stream>>>(srcA, dstA, ebCursor, ebuf, E);
    bucket_build    <<<NB, 256, 0, stream>>>(ebuf, ebStart, ebCursor, csrStart,
                                             csr_src, startArr, deg, dinv);

    gemm_mfma<1>  <<<gb, 256, 0, stream>>>(x, W1, h, N_NODES);
    agg_ln_elu<1> <<<ab, 256, 0, stream>>>(h, csr_src, startArr, deg, dinv,
                                           b1, g1, be1, x2b);
    gemm_mfma<0>  <<<gb, 256, 0, stream>>>(x2b, W2, h, N_NODES);
    agg_ln_elu<0> <<<ab, 256, 0, stream>>>(h, csr_src, startArr, deg, dinv,
                                           b2, g2, be2, outp);
}

// Round 5
// 285.636 us; speedup vs baseline: 2.6404x; 1.0339x over previous
//
#include <hip/hip_runtime.h>
#include <hip/hip_bf16.h>
#include <math.h>

#define N_NODES 50000
#define D 128
#define LN_EPS 1e-5f
#define NB 391            // ceil(50000/128): buckets of 128 dst nodes
#define CHUNK 4096        // edges per partition workgroup
#define GB 782            // gemm blocks (3128 wave-slots for 3125 row-blocks)
#define HB 512            // hist blocks fused behind gemm

typedef unsigned int u32;
typedef unsigned short u16;
typedef __attribute__((ext_vector_type(8))) short bf16x8;
typedef __attribute__((ext_vector_type(4))) float f32x4;

static __device__ __forceinline__ u16 f2bf(float f) {   // RNE f32->bf16
    union { float f; unsigned u; } v; v.f = f;
    unsigned r = v.u + 0x7fff + ((v.u >> 16) & 1);
    return (u16)(r >> 16);
}
static __device__ __forceinline__ float bf2f(u16 b) {
    union { unsigned u; float f; } v; v.u = ((unsigned)b) << 16;
    return v.f;
}

static __device__ __forceinline__ bf16x8 packf8(const float* p) {
    float4 f0 = *(const float4*)p;
    float4 f1 = *(const float4*)(p + 4);
    bf16x8 r;
    r[0] = (short)f2bf(f0.x); r[1] = (short)f2bf(f0.y);
    r[2] = (short)f2bf(f0.z); r[3] = (short)f2bf(f0.w);
    r[4] = (short)f2bf(f1.x); r[5] = (short)f2bf(f1.y);
    r[6] = (short)f2bf(f1.z); r[7] = (short)f2bf(f1.w);
    return r;
}

// ---------- F1: gemm1 (blocks 0..GB-1) || bucket histogram (blocks GB..) ----------
__global__ __launch_bounds__(256) void gemm1_hist(const float* __restrict__ X,
                                                  const float* __restrict__ W,
                                                  u16* __restrict__ H,
                                                  const int* __restrict__ dstA,
                                                  u32* __restrict__ bucketCount, int E) {
    __shared__ __align__(16) u16 WT[D][136];
    __shared__ u32 hist[NB];

    if (blockIdx.x >= GB) {                     // ---- histogram part ----
        for (int b = threadIdx.x; b < NB; b += 256) hist[b] = 0;
        __syncthreads();
        int stride = HB * 256;
        for (int e = (blockIdx.x - GB) * 256 + threadIdx.x; e < E; e += stride)
            atomicAdd(&hist[((u32)dstA[e]) >> 7], 1u);
        __syncthreads();
        for (int b = threadIdx.x; b < NB; b += 256)
            if (hist[b]) atomicAdd(&bucketCount[b], hist[b]);
        return;
    }
    // ---- gemm part: H = bf16(X) @ bf16(W) ----
    for (int idx = threadIdx.x; idx < D * D; idx += 256) {
        int k = idx >> 7, c = idx & 127;
        WT[c][k] = f2bf(W[idx]);
    }
    __syncthreads();

    int lane = threadIdx.x & 63;
    int wid  = threadIdx.x >> 6;
    int r    = lane & 15;
    int kg   = lane >> 4;

    for (int rb = blockIdx.x * 4 + wid; rb < N_NODES / 16; rb += GB * 4) {
        int row0 = rb * 16;
        const float* xp = X + (size_t)(row0 + r) * D + kg * 8;
        bf16x8 a0 = packf8(xp);      bf16x8 a1 = packf8(xp + 32);
        bf16x8 a2 = packf8(xp + 64); bf16x8 a3 = packf8(xp + 96);
#pragma unroll
        for (int tile = 0; tile < 8; ++tile) {
            const u16* wp = &WT[tile * 16 + r][kg * 8];
            f32x4 acc = {0.f, 0.f, 0.f, 0.f};
            acc = __builtin_amdgcn_mfma_f32_16x16x32_bf16(a0, *(const bf16x8*)(wp),      acc, 0, 0, 0);
            acc = __builtin_amdgcn_mfma_f32_16x16x32_bf16(a1, *(const bf16x8*)(wp + 32), acc, 0, 0, 0);
            acc = __builtin_amdgcn_mfma_f32_16x16x32_bf16(a2, *(const bf16x8*)(wp + 64), acc, 0, 0, 0);
            acc = __builtin_amdgcn_mfma_f32_16x16x32_bf16(a3, *(const bf16x8*)(wp + 96), acc, 0, 0, 0);
#pragma unroll
            for (int i = 0; i < 4; ++i)
                H[(size_t)(row0 + kg * 4 + i) * D + tile * 16 + r] = f2bf(acc[i]);
        }
    }
}

// ---------- standalone gemm2 (bf16 in) ----------
__global__ __launch_bounds__(256) void gemm_mfma(const u16* __restrict__ Xb,
                                                 const float* __restrict__ W,
                                                 u16* __restrict__ H) {
    __shared__ __align__(16) u16 WT[D][136];
    for (int idx = threadIdx.x; idx < D * D; idx += 256) {
        int k = idx >> 7, c = idx & 127;
        WT[c][k] = f2bf(W[idx]);
    }
    __syncthreads();
    int lane = threadIdx.x & 63;
    int wid  = threadIdx.x >> 6;
    int r    = lane & 15;
    int kg   = lane >> 4;
    for (int rb = blockIdx.x * 4 + wid; rb < N_NODES / 16; rb += GB * 4) {
        int row0 = rb * 16;
        const u16* xp = Xb + (size_t)(row0 + r) * D + kg * 8;
        bf16x8 a0 = *(const bf16x8*)(xp);      bf16x8 a1 = *(const bf16x8*)(xp + 32);
        bf16x8 a2 = *(const bf16x8*)(xp + 64); bf16x8 a3 = *(const bf16x8*)(xp + 96);
#pragma unroll
        for (int tile = 0; tile < 8; ++tile) {
            const u16* wp = &WT[tile * 16 + r][kg * 8];
            f32x4 acc = {0.f, 0.f, 0.f, 0.f};
            acc = __builtin_amdgcn_mfma_f32_16x16x32_bf16(a0, *(const bf16x8*)(wp),      acc, 0, 0, 0);
            acc = __builtin_amdgcn_mfma_f32_16x16x32_bf16(a1, *(const bf16x8*)(wp + 32), acc, 0, 0, 0);
            acc = __builtin_amdgcn_mfma_f32_16x16x32_bf16(a2, *(const bf16x8*)(wp + 64), acc, 0, 0, 0);
            acc = __builtin_amdgcn_mfma_f32_16x16x32_bf16(a3, *(const bf16x8*)(wp + 96), acc, 0, 0, 0);
#pragma unroll
            for (int i = 0; i < 4; ++i)
                H[(size_t)(row0 + kg * 4 + i) * D + tile * 16 + r] = f2bf(acc[i]);
        }
    }
}

// ---------- F2: partition (512 thr; per-block LDS scan replaces scan_kernel) ----------
__global__ __launch_bounds__(512) void partition_kernel(const int* __restrict__ srcA,
                                                        const int* __restrict__ dstA,
                                                        const u32* __restrict__ bucketCount,
                                                        u32* __restrict__ relCursor,
                                                        u32* __restrict__ ebuf, int E) {
    __shared__ u32 sc[512];
    __shared__ u32 ebS[NB], cntA[NB], cntB[NB], base[NB];
    int t = threadIdx.x;
    u32 bc = (t < NB) ? bucketCount[t] : 0u;
    sc[t] = bc;
    for (int b = t; b < NB; b += 512) { cntA[b] = 0; cntB[b] = 0; }
    __syncthreads();
    for (int off = 1; off < 512; off <<= 1) {        // inclusive scan
        u32 v = sc[t] + ((t >= off) ? sc[t - off] : 0u);
        __syncthreads();
        sc[t] = v;
        __syncthreads();
    }
    if (t < NB) ebS[t] = sc[t] - bc;                 // exclusive: edges before bucket
    __syncthreads();

    int e0 = blockIdx.x * CHUNK;
    int e1 = min(e0 + CHUNK, E);
    for (int e = e0 + t; e < e1; e += 512)
        atomicAdd(&cntA[((u32)dstA[e]) >> 7], 1u);
    __syncthreads();
    for (int b = t; b < NB; b += 512)
        if (cntA[b]) base[b] = ebS[b] + atomicAdd(&relCursor[b], cntA[b]);
    __syncthreads();
    for (int e = e0 + t; e < e1; e += 512) {
        u32 d = (u32)dstA[e], sv = (u32)srcA[e];
        u32 b = d >> 7;
        u32 off = atomicAdd(&cntB[b], 1u);
        ebuf[base[b] + off] = (sv << 16) | d;        // src,dst < 65536
    }
}

// ---------- F3: per-bucket CSR build (in-block prefix over bucketCount) ----------
__global__ __launch_bounds__(256) void bucket_build(const u32* __restrict__ ebuf,
                                                    const u32* __restrict__ bucketCount,
                                                    u16* __restrict__ csr_src,
                                                    int* __restrict__ startArr,
                                                    int* __restrict__ deg,
                                                    float* __restrict__ dinv) {
    int b = blockIdx.x, t = threadIdx.x;
    __shared__ u32 red[256];
    __shared__ u32 cnt[128], sc[128], cur[128];
    u32 partial = 0;
    for (int i = t; i < b; i += 256) partial += bucketCount[i];
    red[t] = partial;
    if (t < 128) cnt[t] = 0;
    __syncthreads();
    for (int off = 128; off > 0; off >>= 1) {
        if (t < off) red[t] += red[t + off];
        __syncthreads();
    }
    u32 eb0 = red[0];                          // ebStart[b]
    u32 eb1 = eb0 + bucketCount[b];
    u32 cs  = eb0 + 128u * (u32)b;             // csrStart[b]

    int nodeBase = b << 7;
    int nNodes = min(128, N_NODES - nodeBase);
    for (u32 e = eb0 + t; e < eb1; e += 256)
        atomicAdd(&cnt[ebuf[e] & 127u], 1u);
    __syncthreads();
    if (t < 128) sc[t] = (t < nNodes) ? cnt[t] + 1u : 0u;   // +1 self-loop
    __syncthreads();
    for (int off = 1; off < 128; off <<= 1) {
        u32 v = 0;
        if (t < 128) v = sc[t] + ((t >= off) ? sc[t - off] : 0u);
        __syncthreads();
        if (t < 128) sc[t] = v;
        __syncthreads();
    }
    if (t < nNodes) {
        u32 val = cnt[t] + 1u;
        u32 excl = sc[t] - val;
        int i = nodeBase + t;
        deg[i] = (int)val;
        dinv[i] = rsqrtf((float)val);
        u32 sa = cs + excl;
        startArr[i] = (int)sa;
        csr_src[sa] = (u16)i;                  // self-loop first
        cur[t] = excl + 1u;
    }
    __syncthreads();
    for (u32 e = eb0 + t; e < eb1; e += 256) {
        u32 p = ebuf[e];
        u32 pos = atomicAdd(&cur[p & 127u], 1u);
        csr_src[cs + pos] = (u16)(p >> 16);
    }
}

// ------- gather-aggregate + bias + LN + ELU; 2 nodes/wave, 8-edge unroll -------
template <int WRITE_BF16>
__global__ __launch_bounds__(256) void agg_ln_elu(
        const u16* __restrict__ H, const u16* __restrict__ csr_src,
        const int* __restrict__ startArr, const int* __restrict__ deg,
        const float* __restrict__ dinv,
        const float* __restrict__ bias, const float* __restrict__ gamma,
        const float* __restrict__ beta, void* __restrict__ outv) {
    int lane = threadIdx.x & 63;
    int wid  = threadIdx.x >> 6;
    int half = lane >> 5;
    int l    = lane & 31;
    int node = blockIdx.x * 8 + wid * 2 + half;   // 6250 blocks * 8 = 50000 exact

    int s    = startArr[node];
    int cnt  = deg[node];
    float dn = dinv[node];
    int c0   = l * 4;

    float a0 = 0.f, a1 = 0.f, a2 = 0.f, a3 = 0.f;   // bank A (even edges)
    float b0 = 0.f, b1 = 0.f, b2 = 0.f, b3 = 0.f;   // bank B (odd edges)
    int j = 0;
    for (; j + 8 <= cnt; j += 8) {
        u32 i0 = csr_src[s + j],     i1 = csr_src[s + j + 1];
        u32 i2 = csr_src[s + j + 2], i3 = csr_src[s + j + 3];
        u32 i4 = csr_src[s + j + 4], i5 = csr_src[s + j + 5];
        u32 i6 = csr_src[s + j + 6], i7 = csr_src[s + j + 7];
        float w0 = dinv[i0] * dn, w1 = dinv[i1] * dn;
        float w2 = dinv[i2] * dn, w3 = dinv[i3] * dn;
        float w4 = dinv[i4] * dn, w5 = dinv[i5] * dn;
        float w6 = dinv[i6] * dn, w7 = dinv[i7] * dn;
        ushort4 g0 = *(const ushort4*)&H[(size_t)i0 * D + c0];
        ushort4 g1 = *(const ushort4*)&H[(size_t)i1 * D + c0];
        ushort4 g2 = *(const ushort4*)&H[(size_t)i2 * D + c0];
        ushort4 g3 = *(const ushort4*)&H[(size_t)i3 * D + c0];
        ushort4 g4 = *(const ushort4*)&H[(size_t)i4 * D + c0];
        ushort4 g5 = *(const ushort4*)&H[(size_t)i5 * D + c0];
        ushort4 g6 = *(const ushort4*)&H[(size_t)i6 * D + c0];
        ushort4 g7 = *(const ushort4*)&H[(size_t)i7 * D + c0];
        a0 = fmaf(w0, bf2f(g0.x), a0); a1 = fmaf(w0, bf2f(g0.y), a1);
        a2 = fmaf(w0, bf2f(g0.z), a2); a3 = fmaf(w0, bf2f(g0.w), a3);
        b0 = fmaf(w1, bf2f(g1.x), b0); b1 = fmaf(w1, bf2f(g1.y), b1);
        b2 = fmaf(w1, bf2f(g1.z), b2); b3 = fmaf(w1, bf2f(g1.w), b3);
        a0 = fmaf(w2, bf2f(g2.x), a0); a1 = fmaf(w2, bf2f(g2.y), a1);
        a2 = fmaf(w2, bf2f(g2.z), a2); a3 = fmaf(w2, bf2f(g2.w), a3);
        b0 = fmaf(w3, bf2f(g3.x), b0); b1 = fmaf(w3, bf2f(g3.y), b1);
        b2 = fmaf(w3, bf2f(g3.z), b2); b3 = fmaf(w3, bf2f(g3.w), b3);
        a0 = fmaf(w4, bf2f(g4.x), a0); a1 = fmaf(w4, bf2f(g4.y), a1);
        a2 = fmaf(w4, bf2f(g4.z), a2); a3 = fmaf(w4, bf2f(g4.w), a3);
        b0 = fmaf(w5, bf2f(g5.x), b0); b1 = fmaf(w5, bf2f(g5.y), b1);
        b2 = fmaf(w5, bf2f(g5.z), b2); b3 = fmaf(w5, bf2f(g5.w), b3);
        a0 = fmaf(w6, bf2f(g6.x), a0); a1 = fmaf(w6, bf2f(g6.y), a1);
        a2 = fmaf(w6, bf2f(g6.z), a2); a3 = fmaf(w6, bf2f(g6.w), a3);
        b0 = fmaf(w7, bf2f(g7.x), b0); b1 = fmaf(w7, bf2f(g7.y), b1);
        b2 = fmaf(w7, bf2f(g7.z), b2); b3 = fmaf(w7, bf2f(g7.w), b3);
    }
    for (; j < cnt; ++j) {
        u32 i0 = csr_src[s + j];
        float w0 = dinv[i0] * dn;
        ushort4 g0 = *(const ushort4*)&H[(size_t)i0 * D + c0];
        a0 = fmaf(w0, bf2f(g0.x), a0); a1 = fmaf(w0, bf2f(g0.y), a1);
        a2 = fmaf(w0, bf2f(g0.z), a2); a3 = fmaf(w0, bf2f(g0.w), a3);
    }
    a0 += b0; a1 += b1; a2 += b2; a3 += b3;

    float4 bv = *(const float4*)&bias[c0];
    a0 += bv.x; a1 += bv.y; a2 += bv.z; a3 += bv.w;

    float sum = a0 + a1 + a2 + a3;
    float sq  = a0 * a0 + a1 * a1 + a2 * a2 + a3 * a3;
#pragma unroll
    for (int m = 16; m > 0; m >>= 1) {       // reduce within 32-lane half
        sum += __shfl_xor(sum, m, 64);
        sq  += __shfl_xor(sq,  m, 64);
    }
    float mean = sum * (1.f / 128.f);
    float var  = sq * (1.f / 128.f) - mean * mean;
    float rstd = rsqrtf(var + LN_EPS);

    float4 gv = *(const float4*)&gamma[c0];
    float4 ev = *(const float4*)&beta[c0];
    float y0 = (a0 - mean) * rstd * gv.x + ev.x;
    float y1 = (a1 - mean) * rstd * gv.y + ev.y;
    float y2 = (a2 - mean) * rstd * gv.z + ev.z;
    float y3 = (a3 - mean) * rstd * gv.w + ev.w;
    y0 = y0 > 0.f ? y0 : expm1f(y0);
    y1 = y1 > 0.f ? y1 : expm1f(y1);
    y2 = y2 > 0.f ? y2 : expm1f(y2);
    y3 = y3 > 0.f ? y3 : expm1f(y3);

    if (WRITE_BF16) {
        ushort4 o;
        o.x = f2bf(y0); o.y = f2bf(y1); o.z = f2bf(y2); o.w = f2bf(y3);
        *(ushort4*)((u16*)outv + (size_t)node * D + c0) = o;
    } else {
        f32x4 o = {y0, y1, y2, y3};
        __builtin_nontemporal_store(o, (f32x4*)((float*)outv + (size_t)node * D + c0));
    }
}

// ---------------- launcher ----------------
extern "C" void kernel_launch(void* const* d_in, const int* in_sizes, int n_in,
                              void* d_out, int out_size, void* d_ws, size_t ws_size,
                              hipStream_t stream) {
    const float* x   = (const float*)d_in[0];
    const int*  eidx = (const int*)d_in[1];
    const float* W1  = (const float*)d_in[2];
    const float* b1  = (const float*)d_in[3];
    const float* g1  = (const float*)d_in[4];
    const float* be1 = (const float*)d_in[5];
    const float* W2  = (const float*)d_in[6];
    const float* b2  = (const float*)d_in[7];
    const float* g2  = (const float*)d_in[8];
    const float* be2 = (const float*)d_in[9];

    int E = in_sizes[1] / 2;
    const int* srcA = eidx;
    const int* dstA = eidx + E;

    char* p = (char*)d_ws;
    auto alloc = [&](size_t bytes) {
        char* r = p;
        p += (bytes + 255) & ~(size_t)255;
        return r;
    };
    u32*   ctr      = (u32*)alloc((size_t)1024 * 4);   // [0..511]=bucketCount, [512..]=relCursor
    u32*   ebuf     = (u32*)alloc((size_t)E * 4);
    u16*   csr_src  = (u16*)alloc((size_t)(E + N_NODES) * 2);
    int*   startArr = (int*)alloc((size_t)N_NODES * 4);
    int*   deg      = (int*)alloc((size_t)N_NODES * 4);
    float* dinv     = (float*)alloc((size_t)N_NODES * 4);
    u16*   h        = (u16*)alloc((size_t)N_NODES * D * 2);
    u16*   x2b      = (u16*)alloc((size_t)N_NODES * D * 2);
    float* outp     = (float*)d_out;

    u32* bucketCount = ctr;
    u32* relCursor   = ctr + 512;

    int pb = (E + CHUNK - 1) / CHUNK;          // 391 partition blocks
    int ab = N_NODES / 8;                      // 6250 agg blocks (exact)

    hipMemsetAsync(ctr, 0, 1024 * 4, stream);
    gemm1_hist      <<<GB + HB, 256, 0, stream>>>(x, W1, h, dstA, bucketCount, E);
    partition_kernel<<<pb, 512, 0, stream>>>(srcA, dstA, bucketCount, relCursor, ebuf, E);
    bucket_build    <<<NB, 256, 0, stream>>>(ebuf, bucketCount, csr_src, startArr, deg, dinv);
    agg_ln_elu<1>   <<<ab, 256, 0, stream>>>(h, csr_src, startArr, deg, dinv,
                                             b1, g1, be1, x2b);
    gemm_mfma       <<<GB, 256, 0, stream>>>(x2b, W2, h);
    agg_ln_elu<0>   <<<ab, 256, 0, stream>>>(h, csr_src, startArr, deg, dinv,
                                             b2, g2, be2, outp);
}